// Round 16
// baseline (43.347 us; speedup 1.0000x reference)
//
#include <hip/hip_runtime.h>
#include <hip/hip_bf16.h>

#define N_DIM   3072
#define BATCH_N 8192
#define K_FIX   30

typedef __attribute__((ext_vector_type(8)))  short short8v;   // 8 bf16
typedef __attribute__((ext_vector_type(16))) float f32x16;

#define CG     32
#define NCG    (N_DIM / CG)          // 96 col groups
#define BCOLS  256                   // out cols per block (8 waves)
#define NCT    (N_DIM / BCOLS)       // 12 col tiles
#define NRG    (BATCH_N / 32)        // 256 row tiles (32 rows per block)
#define PGRAN  72                    // LDS granules (16B) per row (288 cols)
#define NGRAN  (32 * PGRAN)          // 2304 granules per block (36,864 B)
#define NSTG   (NGRAN / 64)          // 36 gload_lds instructions per block
#define BTAB_BYTES (NCG * 4 * 64 * sizeof(short8v))   // 393,216 B

static __device__ __forceinline__ short bfs(float f) {
    __hip_bfloat16 h = __float2bfloat16(f);       // RNE
    return __builtin_bit_cast(short, h);
}

static __device__ __forceinline__ short8v pack8(const float4 a, const float4 b) {
    short8v r;
    r[0] = bfs(a.x); r[1] = bfs(a.y); r[2] = bfs(a.z); r[3] = bfs(a.w);
    r[4] = bfs(b.x); r[5] = bfs(b.y); r[6] = bfs(b.z); r[7] = bfs(b.w);
    return r;
}

// ---- B-fragment build (band of W^T) ----
// Bf[step][jj]: k = 16*step + hi*8 + jj, i = j + 32 - k, B = V[i][cg0-32+k].
static __device__ __forceinline__ short8v build_bfrag(
    const float* __restrict__ V, int cg0, int j, int hi, int step)
{
    short8v v8;
    #pragma unroll
    for (int jj = 0; jj < 8; ++jj) {
        const int k = 16 * step + hi * 8 + jj;
        const int i = j + 32 - k;
        short v = 0;
        if (i >= 0 && i < K_FIX) {
            int c = cg0 - 32 + k;
            if (c < 0) c += N_DIM;
            v = bfs(V[(size_t)i * N_DIM + c]);
        }
        v8[jj] = v;
    }
    return v8;
}

// ---------------- kernel 1: btab build only (96 blocks, ~1-2 us) ------------
// R15's prep launched 1536 blocks (general-fallback grid) that each scanned
// dp and exited -- ~2-4 us of sweep.  The general fallback now lives in
// kernel 2 (register-light scalar path), so prep is exactly NCG blocks.
__global__ __launch_bounds__(256)
void fc_build_btab(const float* __restrict__ V, const int* __restrict__ dp,
                   short8v* __restrict__ btab)
{
    bool contig = true;
    #pragma unroll
    for (int i = 0; i < K_FIX; ++i) contig = contig && (dp[i] == i);
    if (!contig) return;

    const int cgi  = (int)blockIdx.x;
    const int step = (int)threadIdx.x >> 6;
    const int lane = (int)threadIdx.x & 63;
    btab[(cgi * 4 + step) * 64 + lane] =
        build_bfrag(V, cgi * CG, lane & 31, lane >> 5, step);
}

// ---------------- kernel 2: global_load_lds MFMA band-GEMM ------------------
// One 512-thread block = 8 waves x one 32x32 tile; ctile-major block order
// (R15: 256 consecutive blocks share one btab slice + x column window).
// Staging: PGRAN=72 (288 cols, 1.125x halo vs R15's 1.25x), linear LDS dest
// via gload_lds, inverse-XOR ^(row&7) on the global source.  Since 72%8==0,
// read bank-class = (g%8)^(j&7) -- identical distribution to the measured-
// 0-conflict R12/R15 ^15 variant -- and the XOR permutes granules WITHIN
// 128B blocks, so staging source segments are exactly linear 128B.
// C/D layout (m74/m101): col = lane&31, row = (reg&3)+8*(reg>>2)+4*(lane>>5).
template<bool USE_TAB>
__global__ __launch_bounds__(512)
void fc_diag_mfma32(const float* __restrict__ x, const float* __restrict__ V,
                    const int* __restrict__ dp, const short8v* __restrict__ btab,
                    float* __restrict__ out)
{
    __shared__ float Xs[NGRAN * 4];          // 36,864 B

    const int tid   = (int)threadIdx.x;
    const int lane  = tid & 63;
    const int wv    = tid >> 6;              // 8 waves
    const int ctile = (int)blockIdx.x / NRG;     // ctile-major (locality)
    const int rtile = (int)blockIdx.x % NRG;
    const int C0 = ctile * BCOLS;
    const int b0 = rtile * 32;

    bool ok = true;
    #pragma unroll
    for (int i = 0; i < K_FIX; ++i) ok = ok && (dp[i] == i);

    if (!ok) {
        // ---- general fallback (arbitrary diag values; never taken here).
        // Register-light on purpose: no arrays, unroll 1, so the contig
        // path keeps VGPR<=64 (8 waves/SIMD).
        const int col = C0 + (tid & 255);
        const int rh  = tid >> 8;            // 0/1 -> 16 rows each
        #pragma unroll 1
        for (int rr = 0; rr < 16; ++rr) {
            const int b = b0 + rh * 16 + rr;
            float a = 0.f;
            #pragma unroll 1
            for (int i = 0; i < K_FIX; ++i) {
                int d = dp[i] % N_DIM; if (d < 0) d += N_DIM;
                int c = col - d; if (c < 0) c += N_DIM;
                a = fmaf(x[(size_t)b * N_DIM + c], V[(size_t)d * N_DIM + c], a);
            }
            out[(size_t)b * N_DIM + col] = a;
        }
        return;                              // block-uniform: barrier-safe
    }

    const int cgi = ctile * 8 + wv;          // this wave's 32-col group
    const int j   = lane & 31;               // out col within group / A row
    const int hi  = lane >> 5;

    // ---- B fragments: 4 independent 16B loads (issued first) ----
    short8v Bf[4];
    if (USE_TAB) {
        const short8v* bt = btab + (size_t)cgi * 4 * 64 + lane;
        #pragma unroll
        for (int step = 0; step < 4; ++step)
            Bf[step] = bt[(size_t)step * 64];
    } else {
        #pragma unroll
        for (int step = 0; step < 4; ++step)
            Bf[step] = build_bfrag(V, cgi * CG, j, hi, step);
    }

    // ---- stage x tile via global_load_lds (no VGPR round-trip) ----
    // 36 instrs: instr t handled by wave t%8 (waves 0-3 issue 5, 4-7 issue
    // 4; predicate is wave-uniform).  LDS dest linear (HW adds lane*16);
    // per-lane source: row = G/72, slot = G%72, global granule =
    // slot ^ (row&7), col = C0 - 32 + 4*granule, wrapped mod N.
    #pragma unroll
    for (int u = 0; u < 5; ++u) {
        const int t = u * 8 + wv;
        if (t < NSTG) {
            const int G    = t * 64 + lane;
            const int row  = G / PGRAN;
            const int slot = G - row * PGRAN;
            int c = C0 - 32 + 4 * (slot ^ (row & 7));
            if (c < 0) c += N_DIM;           // only ctile==0 wraps
            const float* gp = x + (size_t)(b0 + row) * N_DIM + c;
            __builtin_amdgcn_global_load_lds(
                (const __attribute__((address_space(1))) unsigned int*)gp,
                (__attribute__((address_space(3))) unsigned int*)&Xs[t * 256],
                16, 0, 0);
        }
    }
    asm volatile("s_waitcnt vmcnt(0)" ::: "memory");
    __syncthreads();

    // ---- A frags from LDS + MFMA (verified R10-R15 path, swizzle ^7) ----
    // Wave wv needs logical granules wv*8 + hi*2 + 4*step + {0,1} of row j,
    // read at LDS slot g ^ (j&7), row stride 72 granules.
    f32x16 acc = {0.f,0.f,0.f,0.f, 0.f,0.f,0.f,0.f,
                  0.f,0.f,0.f,0.f, 0.f,0.f,0.f,0.f};
    const int gb = wv * 8 + hi * 2;
    #pragma unroll
    for (int step = 0; step < 4; ++step) {
        const int g0 = (gb + 4 * step + 0) ^ (j & 7);
        const int g1 = (gb + 4 * step + 1) ^ (j & 7);
        const float4 h0 = *reinterpret_cast<const float4*>(&Xs[(j * PGRAN + g0) * 4]);
        const float4 h1 = *reinterpret_cast<const float4*>(&Xs[(j * PGRAN + g1) * 4]);
        acc = __builtin_amdgcn_mfma_f32_32x32x16_bf16(pack8(h0, h1), Bf[step],
                                                      acc, 0, 0, 0);
    }

    // ---- store: col = j, row = (reg&3) + 8*(reg>>2) + 4*hi ----
    float* ob = out + (size_t)b0 * N_DIM + C0 + wv * 32 + j;
    #pragma unroll
    for (int reg = 0; reg < 16; ++reg) {
        const int row = (reg & 3) + 8 * (reg >> 2) + 4 * hi;
        ob[(size_t)row * N_DIM] = acc[reg];
    }
}

// ---------------- naive fallback for K != 30 --------------------------------
__global__ void fc_diag_naive(const float* __restrict__ x, const float* __restrict__ V,
                              const int* __restrict__ dp, int K, float* __restrict__ out)
{
    size_t idx   = (size_t)blockIdx.x * blockDim.x + threadIdx.x;
    size_t total = (size_t)BATCH_N * N_DIM;
    size_t step  = (size_t)gridDim.x * blockDim.x;
    for (; idx < total; idx += step) {
        int b = (int)(idx / N_DIM), r = (int)(idx % N_DIM);
        float acc = 0.f;
        for (int i = 0; i < K; ++i) {
            int d = dp[i] % N_DIM; if (d < 0) d += N_DIM;
            int c = r - d; if (c < 0) c += N_DIM;
            acc = fmaf(x[(size_t)b * N_DIM + c], V[(size_t)d * N_DIM + c], acc);
        }
        out[idx] = acc;
    }
}

extern "C" void kernel_launch(void* const* d_in, const int* in_sizes, int n_in,
                              void* d_out, int out_size, void* d_ws, size_t ws_size,
                              hipStream_t stream)
{
    const float* x  = (const float*)d_in[0];
    const float* V  = (const float*)d_in[1];
    const int*   dp = (const int*)d_in[2];
    float* out = (float*)d_out;
    const int K = in_sizes[2];

    if (K == K_FIX) {
        if (ws_size >= BTAB_BYTES) {
            short8v* btab = (short8v*)d_ws;
            fc_build_btab<<<dim3(NCG), dim3(256), 0, stream>>>(V, dp, btab);
            fc_diag_mfma32<true><<<dim3(NCT * NRG), dim3(512), 0, stream>>>(
                x, V, dp, btab, out);
        } else {
            fc_diag_mfma32<false><<<dim3(NCT * NRG), dim3(512), 0, stream>>>(
                x, V, dp, nullptr, out);
        }
    } else {
        fc_diag_naive<<<dim3(2048), dim3(256), 0, stream>>>(x, V, dp, K, out);
    }
}

// Round 17
// 42.298 us; speedup vs baseline: 1.0248x; 1.0248x over previous
//
#include <hip/hip_runtime.h>
#include <hip/hip_bf16.h>

#define N_DIM   3072
#define BATCH_N 8192
#define K_FIX   30

typedef __attribute__((ext_vector_type(8)))  short short8v;   // 8 bf16
typedef __attribute__((ext_vector_type(16))) float f32x16;

#define CG     32
#define NCG    (N_DIM / CG)          // 96 col groups
#define BCOLS  256                   // out cols per block (8 waves)
#define NCT    (N_DIM / BCOLS)       // 12 col tiles
#define NRG    (BATCH_N / 32)        // 256 row tiles (32 rows per block)
#define PGRAN  72                    // LDS granules (16B) per row (288 cols)
#define NGRAN  (32 * PGRAN)          // 2304 granules per block (36,864 B)
#define NSTG   (NGRAN / 64)          // 36 gload_lds instructions per block
#define BTAB_BYTES (NCG * 4 * 64 * sizeof(short8v))   // 393,216 B

static __device__ __forceinline__ short bfs(float f) {
    __hip_bfloat16 h = __float2bfloat16(f);       // RNE
    return __builtin_bit_cast(short, h);
}

static __device__ __forceinline__ short8v pack8(const float4 a, const float4 b) {
    short8v r;
    r[0] = bfs(a.x); r[1] = bfs(a.y); r[2] = bfs(a.z); r[3] = bfs(a.w);
    r[4] = bfs(b.x); r[5] = bfs(b.y); r[6] = bfs(b.z); r[7] = bfs(b.w);
    return r;
}

// ---- B-fragment build (band of W^T) ----
// Bf[step][jj]: k = 16*step + hi*8 + jj, i = j + 32 - k, B = V[i][cg0-32+k].
static __device__ __forceinline__ short8v build_bfrag(
    const float* __restrict__ V, int cg0, int j, int hi, int step)
{
    short8v v8;
    #pragma unroll
    for (int jj = 0; jj < 8; ++jj) {
        const int k = 16 * step + hi * 8 + jj;
        const int i = j + 32 - k;
        short v = 0;
        if (i >= 0 && i < K_FIX) {
            int c = cg0 - 32 + k;
            if (c < 0) c += N_DIM;
            v = bfs(V[(size_t)i * N_DIM + c]);
        }
        v8[jj] = v;
    }
    return v8;
}

// ---------------- kernel 1: btab build only (96 blocks) ---------------------
__global__ __launch_bounds__(256)
void fc_build_btab(const float* __restrict__ V, const int* __restrict__ dp,
                   short8v* __restrict__ btab)
{
    bool contig = true;
    #pragma unroll
    for (int i = 0; i < K_FIX; ++i) contig = contig && (dp[i] == i);
    if (!contig) return;

    const int cgi  = (int)blockIdx.x;
    const int step = (int)threadIdx.x >> 6;
    const int lane = (int)threadIdx.x & 63;
    btab[(cgi * 4 + step) * 64 + lane] =
        build_bfrag(V, cgi * CG, lane & 31, lane >> 5, step);
}

// ---------------- kernel 2: global_load_lds MFMA band-GEMM ------------------
// R16 structure (verified absmax 0.125) with ONE change: out stores are
// NON-TEMPORAL (out is written once, never re-read -> stream past L2,
// keeping L2/L3 hot for x + btab and easing the write-heavy HBM mix).
template<bool USE_TAB>
__global__ __launch_bounds__(512)
void fc_diag_mfma32(const float* __restrict__ x, const float* __restrict__ V,
                    const int* __restrict__ dp, const short8v* __restrict__ btab,
                    float* __restrict__ out)
{
    __shared__ float Xs[NGRAN * 4];          // 36,864 B

    const int tid   = (int)threadIdx.x;
    const int lane  = tid & 63;
    const int wv    = tid >> 6;              // 8 waves
    const int ctile = (int)blockIdx.x / NRG;     // ctile-major (locality)
    const int rtile = (int)blockIdx.x % NRG;
    const int C0 = ctile * BCOLS;
    const int b0 = rtile * 32;

    bool ok = true;
    #pragma unroll
    for (int i = 0; i < K_FIX; ++i) ok = ok && (dp[i] == i);

    if (!ok) {
        // ---- general fallback (arbitrary diag values; never taken here) ----
        const int col = C0 + (tid & 255);
        const int rh  = tid >> 8;            // 0/1 -> 16 rows each
        #pragma unroll 1
        for (int rr = 0; rr < 16; ++rr) {
            const int b = b0 + rh * 16 + rr;
            float a = 0.f;
            #pragma unroll 1
            for (int i = 0; i < K_FIX; ++i) {
                int d = dp[i] % N_DIM; if (d < 0) d += N_DIM;
                int c = col - d; if (c < 0) c += N_DIM;
                a = fmaf(x[(size_t)b * N_DIM + c], V[(size_t)d * N_DIM + c], a);
            }
            out[(size_t)b * N_DIM + col] = a;
        }
        return;                              // block-uniform: barrier-safe
    }

    const int cgi = ctile * 8 + wv;          // this wave's 32-col group
    const int j   = lane & 31;               // out col within group / A row
    const int hi  = lane >> 5;

    // ---- B fragments: 4 independent 16B loads (issued first) ----
    short8v Bf[4];
    if (USE_TAB) {
        const short8v* bt = btab + (size_t)cgi * 4 * 64 + lane;
        #pragma unroll
        for (int step = 0; step < 4; ++step)
            Bf[step] = bt[(size_t)step * 64];
    } else {
        #pragma unroll
        for (int step = 0; step < 4; ++step)
            Bf[step] = build_bfrag(V, cgi * CG, j, hi, step);
    }

    // ---- stage x tile via global_load_lds (no VGPR round-trip) ----
    // 36 instrs, wave t%8 handles instr t.  LDS dest linear (HW adds
    // lane*16); per-lane source: row = G/72, slot = G%72, global granule =
    // slot ^ (row&7), col = C0 - 32 + 4*granule, wrapped mod N.
    #pragma unroll
    for (int u = 0; u < 5; ++u) {
        const int t = u * 8 + wv;
        if (t < NSTG) {
            const int G    = t * 64 + lane;
            const int row  = G / PGRAN;
            const int slot = G - row * PGRAN;
            int c = C0 - 32 + 4 * (slot ^ (row & 7));
            if (c < 0) c += N_DIM;           // only ctile==0 wraps
            const float* gp = x + (size_t)(b0 + row) * N_DIM + c;
            __builtin_amdgcn_global_load_lds(
                (const __attribute__((address_space(1))) unsigned int*)gp,
                (__attribute__((address_space(3))) unsigned int*)&Xs[t * 256],
                16, 0, 0);
        }
    }
    asm volatile("s_waitcnt vmcnt(0)" ::: "memory");
    __syncthreads();

    // ---- A frags from LDS + MFMA (verified R10-R16 path, swizzle ^7) ----
    f32x16 acc = {0.f,0.f,0.f,0.f, 0.f,0.f,0.f,0.f,
                  0.f,0.f,0.f,0.f, 0.f,0.f,0.f,0.f};
    const int gb = wv * 8 + hi * 2;
    #pragma unroll
    for (int step = 0; step < 4; ++step) {
        const int g0 = (gb + 4 * step + 0) ^ (j & 7);
        const int g1 = (gb + 4 * step + 1) ^ (j & 7);
        const float4 h0 = *reinterpret_cast<const float4*>(&Xs[(j * PGRAN + g0) * 4]);
        const float4 h1 = *reinterpret_cast<const float4*>(&Xs[(j * PGRAN + g1) * 4]);
        acc = __builtin_amdgcn_mfma_f32_32x32x16_bf16(pack8(h0, h1), Bf[step],
                                                      acc, 0, 0, 0);
    }

    // ---- store (NON-TEMPORAL): col = j, row = (reg&3)+8*(reg>>2)+4*hi ----
    float* ob = out + (size_t)b0 * N_DIM + C0 + wv * 32 + j;
    #pragma unroll
    for (int reg = 0; reg < 16; ++reg) {
        const int row = (reg & 3) + 8 * (reg >> 2) + 4 * hi;
        __builtin_nontemporal_store(acc[reg], ob + (size_t)row * N_DIM);
    }
}

// ---------------- naive fallback for K != 30 --------------------------------
__global__ void fc_diag_naive(const float* __restrict__ x, const float* __restrict__ V,
                              const int* __restrict__ dp, int K, float* __restrict__ out)
{
    size_t idx   = (size_t)blockIdx.x * blockDim.x + threadIdx.x;
    size_t total = (size_t)BATCH_N * N_DIM;
    size_t step  = (size_t)gridDim.x * blockDim.x;
    for (; idx < total; idx += step) {
        int b = (int)(idx / N_DIM), r = (int)(idx % N_DIM);
        float acc = 0.f;
        for (int i = 0; i < K; ++i) {
            int d = dp[i] % N_DIM; if (d < 0) d += N_DIM;
            int c = r - d; if (c < 0) c += N_DIM;
            acc = fmaf(x[(size_t)b * N_DIM + c], V[(size_t)d * N_DIM + c], acc);
        }
        out[idx] = acc;
    }
}

extern "C" void kernel_launch(void* const* d_in, const int* in_sizes, int n_in,
                              void* d_out, int out_size, void* d_ws, size_t ws_size,
                              hipStream_t stream)
{
    const float* x  = (const float*)d_in[0];
    const float* V  = (const float*)d_in[1];
    const int*   dp = (const int*)d_in[2];
    float* out = (float*)d_out;
    const int K = in_sizes[2];

    if (K == K_FIX) {
        if (ws_size >= BTAB_BYTES) {
            short8v* btab = (short8v*)d_ws;
            fc_build_btab<<<dim3(NCG), dim3(256), 0, stream>>>(V, dp, btab);
            fc_diag_mfma32<true><<<dim3(NCT * NRG), dim3(512), 0, stream>>>(
                x, V, dp, btab, out);
        } else {
            fc_diag_mfma32<false><<<dim3(NCT * NRG), dim3(512), 0, stream>>>(
                x, V, dp, nullptr, out);
        }
    } else {
        fc_diag_naive<<<dim3(2048), dim3(256), 0, stream>>>(x, V, dp, K, out);
    }
}